// Round 2
// baseline (20991.893 us; speedup 1.0000x reference)
//
#include <hip/hip_runtime.h>
#include <hip/hip_fp16.h>

// Bidirectional 2-layer LSTM: B=32, T=1024, IN=256, H=256.
// ws layout: xg f16 [2][32][1024][1024]      = 134,217,728 B
//            hbuf f32 [2][16][2][2][256]     =     131,072 B   (dir, bgroup, parity, b, j)
//            cnt  int [2 layers][32 grp][32] =       8,192 B   (128 B stride per group)
// total = 134,356,992 B  (< round-0-proven 138,412,032)

#define T_LEN 1024
#define BATCH 32
#define HID   256
#define G4    1024
#define NS    8      // h-slices per (dir, batch-group) = sync-group size
#define NG    16     // batch groups (2 batches each)

struct __align__(8) Half4 { __half x, y, z, w; };

__device__ __forceinline__ float sigm(float x) { return 1.0f / (1.0f + __expf(-x)); }
__device__ __forceinline__ float tanh_fast(float x) {
    float e = __expf(2.f * x);            // inf-safe: e=inf -> 1, e=0 -> -1
    return 1.f - 2.f / (e + 1.f);
}

// ---- projection: xg[dir][m][n] = sum_k A[m][k]*W[n][k] + bih[n] + bhh[n], stored f16 ----
__global__ __launch_bounds__(256) void proj_kernel(
    const float* __restrict__ A, int K,
    const float* __restrict__ Wf, const float* __restrict__ Wr,
    const float* __restrict__ bih_f, const float* __restrict__ bhh_f,
    const float* __restrict__ bih_r, const float* __restrict__ bhh_r,
    __half* __restrict__ xg)
{
    const int dir = blockIdx.z;
    const float* __restrict__ W   = dir ? Wr    : Wf;
    const float* __restrict__ bih = dir ? bih_r : bih_f;
    const float* __restrict__ bhh = dir ? bhh_r : bhh_f;
    __half* __restrict__ outp = xg + (size_t)dir * ((size_t)BATCH * T_LEN * G4);

    __shared__ float As[32][132];
    __shared__ float Bs[32][132];

    const int tid = threadIdx.x;
    const int tx  = tid & 15;
    const int ty  = tid >> 4;
    const int tx4 = tx * 4;
    const int ty4 = ty * 4;
    const int m0  = blockIdx.y * 128;
    const int n0  = blockIdx.x * 128;

    float acc[8][8];
    #pragma unroll
    for (int i = 0; i < 8; ++i)
        #pragma unroll
        for (int j = 0; j < 8; ++j) acc[i][j] = 0.f;

    for (int k0 = 0; k0 < K; k0 += 32) {
        #pragma unroll
        for (int it = 0; it < 4; ++it) {
            int f   = tid + it * 256;
            int row = f >> 3;
            int c4  = (f & 7) * 4;
            float4 av = *reinterpret_cast<const float4*>(&A[(size_t)(m0 + row) * K + k0 + c4]);
            float4 bv = *reinterpret_cast<const float4*>(&W[(size_t)(n0 + row) * K + k0 + c4]);
            As[c4 + 0][row] = av.x; As[c4 + 1][row] = av.y;
            As[c4 + 2][row] = av.z; As[c4 + 3][row] = av.w;
            Bs[c4 + 0][row] = bv.x; Bs[c4 + 1][row] = bv.y;
            Bs[c4 + 2][row] = bv.z; Bs[c4 + 3][row] = bv.w;
        }
        __syncthreads();
        #pragma unroll
        for (int k = 0; k < 32; ++k) {
            float4 a0 = *reinterpret_cast<const float4*>(&As[k][ty4]);
            float4 a1 = *reinterpret_cast<const float4*>(&As[k][64 + ty4]);
            float4 b0 = *reinterpret_cast<const float4*>(&Bs[k][tx4]);
            float4 b1 = *reinterpret_cast<const float4*>(&Bs[k][64 + tx4]);
            float a[8] = {a0.x,a0.y,a0.z,a0.w,a1.x,a1.y,a1.z,a1.w};
            float b[8] = {b0.x,b0.y,b0.z,b0.w,b1.x,b1.y,b1.z,b1.w};
            #pragma unroll
            for (int i = 0; i < 8; ++i)
                #pragma unroll
                for (int j = 0; j < 8; ++j)
                    acc[i][j] = fmaf(a[i], b[j], acc[i][j]);
        }
        __syncthreads();
    }

    float bb[8];
    #pragma unroll
    for (int j = 0; j < 8; ++j) {
        int n = n0 + ((j < 4) ? (tx4 + j) : (64 + tx4 + (j - 4)));
        bb[j] = bih[n] + bhh[n];
    }
    #pragma unroll
    for (int i = 0; i < 8; ++i) {
        int m = m0 + ((i < 4) ? (ty4 + i) : (64 + ty4 + (i - 4)));
        Half4 v0, v1;
        v0.x = __float2half(acc[i][0] + bb[0]);
        v0.y = __float2half(acc[i][1] + bb[1]);
        v0.z = __float2half(acc[i][2] + bb[2]);
        v0.w = __float2half(acc[i][3] + bb[3]);
        v1.x = __float2half(acc[i][4] + bb[4]);
        v1.y = __float2half(acc[i][5] + bb[5]);
        v1.z = __float2half(acc[i][6] + bb[6]);
        v1.w = __float2half(acc[i][7] + bb[7]);
        *reinterpret_cast<Half4*>(&outp[(size_t)m * G4 + n0 + tx4])      = v0;
        *reinterpret_cast<Half4*>(&outp[(size_t)m * G4 + n0 + 64 + tx4]) = v1;
    }
}

// ---- cooperative recurrence: 256 wgs, LDS-resident weight slices, cross-wg h exchange ----
// wg = (dir d, batch-group g [2 batches], slice s [32 h-idx -> 128 gate cols]).
// bid = a*64 + m*8 + x ; gid = a*8 + x (0..31): d=gid>>4, g=gid&15, s=m.
// Group members share bid%8 -> same XCD under default round-robin placement (perf only).
extern "C" __global__ __launch_bounds__(256, 1) void recur2_kernel(
    const __half* __restrict__ xg,
    const float* __restrict__ Whh_f,   // [1024][256]
    const float* __restrict__ Whh_r,
    float* __restrict__ outp,          // [32][1024][512]
    float* __restrict__ hbuf,          // [2][16][2][2][256]
    int* __restrict__ cnt)             // this layer's region: [32 groups][32 ints]
{
    extern __shared__ float smem[];
    float* Wl  = smem;                 // [256][128]  = 131072 B
    float* hl  = smem + 32768;         // [2][256]    =   2048 B
    float* scr = hl + 512;             // [256][4]    =   4096 B

    const int tid = threadIdx.x;
    const int bid = blockIdx.x;
    const int x = bid & 7, m = (bid >> 3) & 7, a = bid >> 6;
    const int gid = a * 8 + x;
    const int d = gid >> 4;
    const int g = gid & 15;
    const int s = m;
    const float* __restrict__ Whh = d ? Whh_r : Whh_f;

    // --- one-time: load weight slice into LDS (coalesced along k) ---
    {
        const int lane_k  = (tid & 63) * 4;
        const int offbase = tid >> 6;
        for (int i = 0; i < 32; ++i) {
            int off = i * 4 + offbase;                       // 0..127 packed col
            int n   = ((off >> 5) << 8) + s * 32 + (off & 31);   // global gate col
            float4 wv = *reinterpret_cast<const float4*>(&Whh[(size_t)n * HID + lane_k]);
            Wl[(lane_k + 0) * 128 + off] = wv.x;
            Wl[(lane_k + 1) * 128 + off] = wv.y;
            Wl[(lane_k + 2) * 128 + off] = wv.z;
            Wl[(lane_k + 3) * 128 + off] = wv.w;
        }
    }

    float* hb = hbuf + (size_t)(d * NG + g) * 2 * (2 * HID);   // [parity][2][256]
    int*   cp = cnt + (d * NG + g) * 32;

    // h[-1] = 0 into parity-1 own slots
    const int bi0 = tid >> 5, jl0 = tid & 31;
    if (tid < 64) {
        __hip_atomic_store(&hb[1 * (2 * HID) + bi0 * HID + s * 32 + jl0], 0.f,
                           __ATOMIC_RELAXED, __HIP_MEMORY_SCOPE_AGENT);
    }
    __syncthreads();
    if (tid == 0) {
        __threadfence();
        __hip_atomic_fetch_add(cp, 1, __ATOMIC_RELEASE, __HIP_MEMORY_SCOPE_AGENT);
    }

    // main-loop thread roles
    const int ks    = tid >> 6;          // k-range 0..3
    const int bi    = (tid >> 5) & 1;    // batch within pair
    const int quad  = tid & 31;          // 4-col quad within 128
    const int kbase = ks * 64;
    const int q     = quad >> 3;
    const int n_my  = (q << 8) + s * 32 + (quad & 7) * 4;
    const int b_my  = g * 2 + bi;
    const __half* __restrict__ xgp =
        xg + ((size_t)(d * BATCH + b_my)) * T_LEN * G4 + n_my;

    float c_state = 0.f;                 // valid for tid<64: cell of (bi0, s*32+jl0)

    for (int st = 0; st < T_LEN; ++st) {
        const int t = d ? (T_LEN - 1 - st) : st;

        if (tid == 0) {
            const int target = (st + 1) * NS;
            while (__hip_atomic_load(cp, __ATOMIC_ACQUIRE, __HIP_MEMORY_SCOPE_AGENT) < target)
                __builtin_amdgcn_s_sleep(1);
        }
        __syncthreads();

        // stage h[st-1] (parity (st+1)&1) into LDS
        {
            const float* hsrc = hb + ((st + 1) & 1) * (2 * HID);
            int i0 = tid * 2;
            float v0 = __hip_atomic_load(&hsrc[i0],     __ATOMIC_RELAXED, __HIP_MEMORY_SCOPE_AGENT);
            float v1 = __hip_atomic_load(&hsrc[i0 + 1], __ATOMIC_RELAXED, __HIP_MEMORY_SCOPE_AGENT);
            hl[i0] = v0; hl[i0 + 1] = v1;
        }
        __syncthreads();

        // partial gates: 4 cols over this thread's 64-k range
        float4 acc;
        if (ks == 0) {
            const __half* xr = xgp + (size_t)t * G4;
            __half2 xa = *reinterpret_cast<const __half2*>(xr);
            __half2 xb = *reinterpret_cast<const __half2*>(xr + 2);
            float2 fa = __half22float2(xa), fb = __half22float2(xb);
            acc.x = fa.x; acc.y = fa.y; acc.z = fb.x; acc.w = fb.y;
        } else {
            acc.x = acc.y = acc.z = acc.w = 0.f;
        }
        {
            const float* hP = hl + bi * HID + kbase;
            const float* wP = Wl + kbase * 128 + quad * 4;
            #pragma unroll 4
            for (int k = 0; k < 64; k += 4) {
                float4 h4 = *reinterpret_cast<const float4*>(&hP[k]);
                float4 w0 = *reinterpret_cast<const float4*>(&wP[(k + 0) * 128]);
                float4 w1 = *reinterpret_cast<const float4*>(&wP[(k + 1) * 128]);
                float4 w2 = *reinterpret_cast<const float4*>(&wP[(k + 2) * 128]);
                float4 w3 = *reinterpret_cast<const float4*>(&wP[(k + 3) * 128]);
                acc.x = fmaf(h4.x, w0.x, acc.x); acc.y = fmaf(h4.x, w0.y, acc.y);
                acc.z = fmaf(h4.x, w0.z, acc.z); acc.w = fmaf(h4.x, w0.w, acc.w);
                acc.x = fmaf(h4.y, w1.x, acc.x); acc.y = fmaf(h4.y, w1.y, acc.y);
                acc.z = fmaf(h4.y, w1.z, acc.z); acc.w = fmaf(h4.y, w1.w, acc.w);
                acc.x = fmaf(h4.z, w2.x, acc.x); acc.y = fmaf(h4.z, w2.y, acc.y);
                acc.z = fmaf(h4.z, w2.z, acc.z); acc.w = fmaf(h4.z, w2.w, acc.w);
                acc.x = fmaf(h4.w, w3.x, acc.x); acc.y = fmaf(h4.w, w3.y, acc.y);
                acc.z = fmaf(h4.w, w3.z, acc.z); acc.w = fmaf(h4.w, w3.w, acc.w);
            }
        }
        *reinterpret_cast<float4*>(&scr[tid * 4]) = acc;
        __syncthreads();

        if (tid < 64) {
            float gv[4];
            #pragma unroll
            for (int qq = 0; qq < 4; ++qq) {
                int base = qq * 32 + jl0;                    // packed col 0..127
                float sum = 0.f;
                #pragma unroll
                for (int kk = 0; kk < 4; ++kk)
                    sum += scr[(kk * 64 + bi0 * 32 + (base >> 2)) * 4 + (base & 3)];
                gv[qq] = sum;
            }
            float ii = sigm(gv[0]);
            float ff = sigm(gv[1]);
            float gg = tanh_fast(gv[2]);
            float oo = sigm(gv[3]);
            c_state = ff * c_state + ii * gg;
            float h = oo * tanh_fast(c_state);
            int j = s * 32 + jl0;
            __hip_atomic_store(&hb[(st & 1) * (2 * HID) + bi0 * HID + j], h,
                               __ATOMIC_RELAXED, __HIP_MEMORY_SCOPE_AGENT);
            int b = g * 2 + bi0;
            outp[((size_t)b * T_LEN + t) * (2 * HID) + d * HID + j] = h;
        }
        __syncthreads();   // all h stores drained (vmcnt 0) + scr/hl reads done

        if (tid == 0 && st < T_LEN - 1) {
            __threadfence();
            __hip_atomic_fetch_add(cp, 1, __ATOMIC_RELEASE, __HIP_MEMORY_SCOPE_AGENT);
        }
    }
}

#define RECUR_LDS 137216u

extern "C" void kernel_launch(void* const* d_in, const int* in_sizes, int n_in,
                              void* d_out, int out_size, void* d_ws, size_t ws_size,
                              hipStream_t stream)
{
    const float* x       = (const float*)d_in[0];
    const float* W_ih_f0 = (const float*)d_in[1];
    const float* W_hh_f0 = (const float*)d_in[2];
    const float* b_ih_f0 = (const float*)d_in[3];
    const float* b_hh_f0 = (const float*)d_in[4];
    const float* W_ih_r0 = (const float*)d_in[5];
    const float* W_hh_r0 = (const float*)d_in[6];
    const float* b_ih_r0 = (const float*)d_in[7];
    const float* b_hh_r0 = (const float*)d_in[8];
    const float* W_ih_f1 = (const float*)d_in[9];
    const float* W_hh_f1 = (const float*)d_in[10];
    const float* b_ih_f1 = (const float*)d_in[11];
    const float* b_hh_f1 = (const float*)d_in[12];
    const float* W_ih_r1 = (const float*)d_in[13];
    const float* W_hh_r1 = (const float*)d_in[14];
    const float* b_ih_r1 = (const float*)d_in[15];
    const float* b_hh_r1 = (const float*)d_in[16];

    float* outp = (float*)d_out;

    __half* xg = (__half*)d_ws;
    const size_t xg_bytes = (size_t)2 * BATCH * T_LEN * G4 * sizeof(__half); // 134,217,728
    float* hbuf = (float*)((char*)d_ws + xg_bytes);
    const size_t hbuf_bytes = (size_t)2 * NG * 2 * 2 * HID * sizeof(float);  // 131,072
    int* cnt = (int*)((char*)d_ws + xg_bytes + hbuf_bytes);                  // 8,192 B (2 layers)

    hipFuncSetAttribute(reinterpret_cast<const void*>(recur2_kernel),
                        hipFuncAttributeMaxDynamicSharedMemorySize, RECUR_LDS);

    // zero both layers' sync counters (captured each replay)
    hipMemsetAsync(cnt, 0, 8192, stream);

    // ---- layer 0 ----
    proj_kernel<<<dim3(8, 256, 2), 256, 0, stream>>>(x, 256, W_ih_f0, W_ih_r0,
        b_ih_f0, b_hh_f0, b_ih_r0, b_hh_r0, xg);
    {
        const __half* xg_c = xg;
        int* cntL = cnt;
        void* args[] = {(void*)&xg_c, (void*)&W_hh_f0, (void*)&W_hh_r0,
                        (void*)&outp, (void*)&hbuf, (void*)&cntL};
        hipLaunchCooperativeKernel(reinterpret_cast<const void*>(recur2_kernel),
                                   dim3(256), dim3(256), args, RECUR_LDS, stream);
    }

    // ---- layer 1 ----
    proj_kernel<<<dim3(8, 256, 2), 256, 0, stream>>>(outp, 512, W_ih_f1, W_ih_r1,
        b_ih_f1, b_hh_f1, b_ih_r1, b_hh_r1, xg);
    {
        const __half* xg_c = xg;
        int* cntL = cnt + 2048 / sizeof(int) * 0 + 1024;   // second layer's 4 KB region
        void* args[] = {(void*)&xg_c, (void*)&W_hh_f1, (void*)&W_hh_r1,
                        (void*)&outp, (void*)&hbuf, (void*)&cntL};
        hipLaunchCooperativeKernel(reinterpret_cast<const void*>(recur2_kernel),
                                   dim3(256), dim3(256), args, RECUR_LDS, stream);
    }
}

// Round 3
// 5764.082 us; speedup vs baseline: 3.6418x; 3.6418x over previous
//
#include <hip/hip_runtime.h>
#include <hip/hip_fp16.h>

// Bidirectional 2-layer LSTM: B=32, T=1024, IN=256, H=256.
// ws layout: xg  f16 [2][32][1024][1024]          = 134,217,728 B
//            hbt u64 [2][16][2 parity][2 b][256]  =     262,144 B  (tagged h exchange)
// total = 134,479,872 B
//
// Tag protocol (per layer, base B):  producer at step st stores (B+st+1, h) into
// parity st&1; consumer at step st polls parity (st+1)&1 for tag B+st.
//   - product of step st is consumed at st+1: expects B+st+1 at parity (st+2)&1 = st&1. OK
//   - init (h[-1]=0) stored with tag B at parity 1; step 0 expects B at parity 1. OK
//   - slot overwrite at step st+1 requires writer to have consumed all step-st tags,
//     which requires every wg to have finished its step-st reads of that slot. OK
// L0 base=1 (tags 1..1025), L1 base=4096 (tags 4096..5120): disjoint; hbt is
// memset to 0 each launch so no stale tag can pre-match.

#define T_LEN 1024
#define BATCH 32
#define HID   256
#define G4    1024
#define NS    8      // h-slices per (dir, batch-group)
#define NG    16     // batch groups (2 batches each)

struct __align__(8) Half4 { __half x, y, z, w; };

__device__ __forceinline__ float sigm(float x) { return 1.0f / (1.0f + __expf(-x)); }
__device__ __forceinline__ float tanh_fast(float x) {
    float e = __expf(2.f * x);            // inf-safe: e=inf -> 1, e=0 -> -1
    return 1.f - 2.f / (e + 1.f);
}

// ---- projection: xg[dir][m][n] = sum_k A[m][k]*W[n][k] + bih[n] + bhh[n], stored f16 ----
__global__ __launch_bounds__(256) void proj_kernel(
    const float* __restrict__ A, int K,
    const float* __restrict__ Wf, const float* __restrict__ Wr,
    const float* __restrict__ bih_f, const float* __restrict__ bhh_f,
    const float* __restrict__ bih_r, const float* __restrict__ bhh_r,
    __half* __restrict__ xg)
{
    const int dir = blockIdx.z;
    const float* __restrict__ W   = dir ? Wr    : Wf;
    const float* __restrict__ bih = dir ? bih_r : bih_f;
    const float* __restrict__ bhh = dir ? bhh_r : bhh_f;
    __half* __restrict__ outp = xg + (size_t)dir * ((size_t)BATCH * T_LEN * G4);

    __shared__ float As[32][132];
    __shared__ float Bs[32][132];

    const int tid = threadIdx.x;
    const int tx  = tid & 15;
    const int ty  = tid >> 4;
    const int tx4 = tx * 4;
    const int ty4 = ty * 4;
    const int m0  = blockIdx.y * 128;
    const int n0  = blockIdx.x * 128;

    float acc[8][8];
    #pragma unroll
    for (int i = 0; i < 8; ++i)
        #pragma unroll
        for (int j = 0; j < 8; ++j) acc[i][j] = 0.f;

    for (int k0 = 0; k0 < K; k0 += 32) {
        #pragma unroll
        for (int it = 0; it < 4; ++it) {
            int f   = tid + it * 256;
            int row = f >> 3;
            int c4  = (f & 7) * 4;
            float4 av = *reinterpret_cast<const float4*>(&A[(size_t)(m0 + row) * K + k0 + c4]);
            float4 bv = *reinterpret_cast<const float4*>(&W[(size_t)(n0 + row) * K + k0 + c4]);
            As[c4 + 0][row] = av.x; As[c4 + 1][row] = av.y;
            As[c4 + 2][row] = av.z; As[c4 + 3][row] = av.w;
            Bs[c4 + 0][row] = bv.x; Bs[c4 + 1][row] = bv.y;
            Bs[c4 + 2][row] = bv.z; Bs[c4 + 3][row] = bv.w;
        }
        __syncthreads();
        #pragma unroll
        for (int k = 0; k < 32; ++k) {
            float4 a0 = *reinterpret_cast<const float4*>(&As[k][ty4]);
            float4 a1 = *reinterpret_cast<const float4*>(&As[k][64 + ty4]);
            float4 b0 = *reinterpret_cast<const float4*>(&Bs[k][tx4]);
            float4 b1 = *reinterpret_cast<const float4*>(&Bs[k][64 + tx4]);
            float a[8] = {a0.x,a0.y,a0.z,a0.w,a1.x,a1.y,a1.z,a1.w};
            float b[8] = {b0.x,b0.y,b0.z,b0.w,b1.x,b1.y,b1.z,b1.w};
            #pragma unroll
            for (int i = 0; i < 8; ++i)
                #pragma unroll
                for (int j = 0; j < 8; ++j)
                    acc[i][j] = fmaf(a[i], b[j], acc[i][j]);
        }
        __syncthreads();
    }

    float bb[8];
    #pragma unroll
    for (int j = 0; j < 8; ++j) {
        int n = n0 + ((j < 4) ? (tx4 + j) : (64 + tx4 + (j - 4)));
        bb[j] = bih[n] + bhh[n];
    }
    #pragma unroll
    for (int i = 0; i < 8; ++i) {
        int m = m0 + ((i < 4) ? (ty4 + i) : (64 + ty4 + (i - 4)));
        Half4 v0, v1;
        v0.x = __float2half(acc[i][0] + bb[0]);
        v0.y = __float2half(acc[i][1] + bb[1]);
        v0.z = __float2half(acc[i][2] + bb[2]);
        v0.w = __float2half(acc[i][3] + bb[3]);
        v1.x = __float2half(acc[i][4] + bb[4]);
        v1.y = __float2half(acc[i][5] + bb[5]);
        v1.z = __float2half(acc[i][6] + bb[6]);
        v1.w = __float2half(acc[i][7] + bb[7]);
        *reinterpret_cast<Half4*>(&outp[(size_t)m * G4 + n0 + tx4])      = v0;
        *reinterpret_cast<Half4*>(&outp[(size_t)m * G4 + n0 + 64 + tx4]) = v1;
    }
}

// ---- cooperative recurrence: fence-free tagged h exchange ----
// wg = (dir d, batch-group g, slice s). bid = a*64 + m*8 + x; gid=a*8+x; d=gid>>4,
// g=gid&15, s=m (group members share bid%8 -> likely same XCD; perf only).
extern "C" __global__ __launch_bounds__(256, 1) void recur2_kernel(
    const __half* __restrict__ xg,
    const float* __restrict__ Whh_f,           // [1024][256]
    const float* __restrict__ Whh_r,
    float* __restrict__ outp,                  // [32][1024][512]
    unsigned long long* __restrict__ hbt,      // [2][16][2][2][256] tagged
    unsigned int tagbase)
{
    extern __shared__ float smem[];
    float* Wl  = smem;                 // [256][128]  = 131072 B
    float* hl  = smem + 32768;         // [2][256]    =   2048 B
    float* scr = hl + 512;             // [256][4]    =   4096 B

    const int tid = threadIdx.x;
    const int bid = blockIdx.x;
    const int x = bid & 7, m = (bid >> 3) & 7, a = bid >> 6;
    const int gid = a * 8 + x;
    const int d = gid >> 4;
    const int g = gid & 15;
    const int s = m;
    const float* __restrict__ Whh = d ? Whh_r : Whh_f;

    // --- one-time: load weight slice into LDS (coalesced along k) ---
    {
        const int lane_k  = (tid & 63) * 4;
        const int offbase = tid >> 6;
        for (int i = 0; i < 32; ++i) {
            int off = i * 4 + offbase;                           // packed col 0..127
            int n   = ((off >> 5) << 8) + s * 32 + (off & 31);   // global gate col
            float4 wv = *reinterpret_cast<const float4*>(&Whh[(size_t)n * HID + lane_k]);
            Wl[(lane_k + 0) * 128 + off] = wv.x;
            Wl[(lane_k + 1) * 128 + off] = wv.y;
            Wl[(lane_k + 2) * 128 + off] = wv.z;
            Wl[(lane_k + 3) * 128 + off] = wv.w;
        }
    }

    unsigned long long* hb = hbt + (size_t)(d * NG + g) * 1024;  // [parity][2][256]

    const int bi0 = tid >> 5, jl0 = tid & 31;
    // init: h[-1]=0, tag=tagbase, parity 1, own 64 slots
    if (tid < 64) {
        __hip_atomic_store(&hb[512 + bi0 * HID + s * 32 + jl0],
                           (unsigned long long)tagbase << 32,
                           __ATOMIC_RELAXED, __HIP_MEMORY_SCOPE_AGENT);
    }

    // main-loop thread roles
    const int ks    = tid >> 6;          // k-range 0..3
    const int bi    = (tid >> 5) & 1;    // batch within pair
    const int quad  = tid & 31;          // 4-col quad within 128
    const int kbase = ks * 64;
    const int q     = quad >> 3;
    const int n_my  = (q << 8) + s * 32 + (quad & 7) * 4;
    const int b_my  = g * 2 + bi;
    const __half* __restrict__ xgp =
        xg + ((size_t)(d * BATCH + b_my)) * T_LEN * G4 + n_my;

    const int i0 = tid * 2;              // this thread's 2 exchange slots
    float c_state = 0.f;                 // tid<64: cell of (bi0, s*32+jl0)

    for (int st = 0; st < T_LEN; ++st) {
        const int t = d ? (T_LEN - 1 - st) : st;

        // prefetch xg (independent of h) before polling
        float xa0 = 0.f, xa1 = 0.f, xa2 = 0.f, xa3 = 0.f;
        if (ks == 0) {
            const __half* xr = xgp + (size_t)t * G4;
            __half2 ha = *reinterpret_cast<const __half2*>(xr);
            __half2 hb2 = *reinterpret_cast<const __half2*>(xr + 2);
            float2 fa = __half22float2(ha), fb = __half22float2(hb2);
            xa0 = fa.x; xa1 = fa.y; xa2 = fb.x; xa3 = fb.y;
        }

        // poll own 2 tagged slots of parity (st+1)&1 for tag tagbase+st
        {
            const unsigned int exp = tagbase + (unsigned)st;
            unsigned long long* hsrc = hb + (size_t)((st + 1) & 1) * 512;
            unsigned long long v0 = __hip_atomic_load(&hsrc[i0],     __ATOMIC_RELAXED, __HIP_MEMORY_SCOPE_AGENT);
            unsigned long long v1 = __hip_atomic_load(&hsrc[i0 + 1], __ATOMIC_RELAXED, __HIP_MEMORY_SCOPE_AGENT);
            while ((unsigned int)(v0 >> 32) != exp)
                v0 = __hip_atomic_load(&hsrc[i0],     __ATOMIC_RELAXED, __HIP_MEMORY_SCOPE_AGENT);
            while ((unsigned int)(v1 >> 32) != exp)
                v1 = __hip_atomic_load(&hsrc[i0 + 1], __ATOMIC_RELAXED, __HIP_MEMORY_SCOPE_AGENT);
            hl[i0]     = __uint_as_float((unsigned int)v0);
            hl[i0 + 1] = __uint_as_float((unsigned int)v1);
        }
        __syncthreads();   // hl ready; also fences scr reuse (see proof in header)

        // partial gates: 4 cols over this thread's 64-k range
        float4 acc;
        acc.x = xa0; acc.y = xa1; acc.z = xa2; acc.w = xa3;
        {
            const float* hP = hl + bi * HID + kbase;
            const float* wP = Wl + kbase * 128 + quad * 4;
            #pragma unroll 4
            for (int k = 0; k < 64; k += 4) {
                float4 h4 = *reinterpret_cast<const float4*>(&hP[k]);
                float4 w0 = *reinterpret_cast<const float4*>(&wP[(k + 0) * 128]);
                float4 w1 = *reinterpret_cast<const float4*>(&wP[(k + 1) * 128]);
                float4 w2 = *reinterpret_cast<const float4*>(&wP[(k + 2) * 128]);
                float4 w3 = *reinterpret_cast<const float4*>(&wP[(k + 3) * 128]);
                acc.x = fmaf(h4.x, w0.x, acc.x); acc.y = fmaf(h4.x, w0.y, acc.y);
                acc.z = fmaf(h4.x, w0.z, acc.z); acc.w = fmaf(h4.x, w0.w, acc.w);
                acc.x = fmaf(h4.y, w1.x, acc.x); acc.y = fmaf(h4.y, w1.y, acc.y);
                acc.z = fmaf(h4.y, w1.z, acc.z); acc.w = fmaf(h4.y, w1.w, acc.w);
                acc.x = fmaf(h4.z, w2.x, acc.x); acc.y = fmaf(h4.z, w2.y, acc.y);
                acc.z = fmaf(h4.z, w2.z, acc.z); acc.w = fmaf(h4.z, w2.w, acc.w);
                acc.x = fmaf(h4.w, w3.x, acc.x); acc.y = fmaf(h4.w, w3.y, acc.y);
                acc.z = fmaf(h4.w, w3.z, acc.z); acc.w = fmaf(h4.w, w3.w, acc.w);
            }
        }
        *reinterpret_cast<float4*>(&scr[tid * 4]) = acc;
        __syncthreads();

        if (tid < 64) {
            float gv[4];
            #pragma unroll
            for (int qq = 0; qq < 4; ++qq) {
                int base = qq * 32 + jl0;                    // packed col 0..127
                float sum = 0.f;
                #pragma unroll
                for (int kk = 0; kk < 4; ++kk)
                    sum += scr[(kk * 64 + bi0 * 32 + (base >> 2)) * 4 + (base & 3)];
                gv[qq] = sum;
            }
            float ii = sigm(gv[0]);
            float ff = sigm(gv[1]);
            float gg = tanh_fast(gv[2]);
            float oo = sigm(gv[3]);
            c_state = ff * c_state + ii * gg;
            float h = oo * tanh_fast(c_state);
            int j = s * 32 + jl0;
            unsigned long long pv =
                ((unsigned long long)(tagbase + (unsigned)st + 1u) << 32) | __float_as_uint(h);
            __hip_atomic_store(&hb[(size_t)(st & 1) * 512 + bi0 * HID + j], pv,
                               __ATOMIC_RELAXED, __HIP_MEMORY_SCOPE_AGENT);
            int b = g * 2 + bi0;
            outp[((size_t)b * T_LEN + t) * (2 * HID) + d * HID + j] = h;
        }
        // no end-of-step barrier needed: next step's post-hl-write barrier orders everything
    }
}

#define RECUR_LDS 137216u

extern "C" void kernel_launch(void* const* d_in, const int* in_sizes, int n_in,
                              void* d_out, int out_size, void* d_ws, size_t ws_size,
                              hipStream_t stream)
{
    const float* x       = (const float*)d_in[0];
    const float* W_ih_f0 = (const float*)d_in[1];
    const float* W_hh_f0 = (const float*)d_in[2];
    const float* b_ih_f0 = (const float*)d_in[3];
    const float* b_hh_f0 = (const float*)d_in[4];
    const float* W_ih_r0 = (const float*)d_in[5];
    const float* W_hh_r0 = (const float*)d_in[6];
    const float* b_ih_r0 = (const float*)d_in[7];
    const float* b_hh_r0 = (const float*)d_in[8];
    const float* W_ih_f1 = (const float*)d_in[9];
    const float* W_hh_f1 = (const float*)d_in[10];
    const float* b_ih_f1 = (const float*)d_in[11];
    const float* b_hh_f1 = (const float*)d_in[12];
    const float* W_ih_r1 = (const float*)d_in[13];
    const float* W_hh_r1 = (const float*)d_in[14];
    const float* b_ih_r1 = (const float*)d_in[15];
    const float* b_hh_r1 = (const float*)d_in[16];

    float* outp = (float*)d_out;

    __half* xg = (__half*)d_ws;
    const size_t xg_bytes = (size_t)2 * BATCH * T_LEN * G4 * sizeof(__half); // 134,217,728
    unsigned long long* hbt = (unsigned long long*)((char*)d_ws + xg_bytes); // 262,144 B

    hipFuncSetAttribute(reinterpret_cast<const void*>(recur2_kernel),
                        hipFuncAttributeMaxDynamicSharedMemorySize, RECUR_LDS);

    // clean tag space every launch (no stale-tag pre-match, fully replay-safe)
    hipMemsetAsync(hbt, 0, 262144, stream);

    // ---- layer 0 ----
    proj_kernel<<<dim3(8, 256, 2), 256, 0, stream>>>(x, 256, W_ih_f0, W_ih_r0,
        b_ih_f0, b_hh_f0, b_ih_r0, b_hh_r0, xg);
    {
        const __half* xg_c = xg;
        unsigned int base0 = 1u;
        void* args[] = {(void*)&xg_c, (void*)&W_hh_f0, (void*)&W_hh_r0,
                        (void*)&outp, (void*)&hbt, (void*)&base0};
        hipLaunchCooperativeKernel(reinterpret_cast<const void*>(recur2_kernel),
                                   dim3(256), dim3(256), args, RECUR_LDS, stream);
    }

    // ---- layer 1 ----
    proj_kernel<<<dim3(8, 256, 2), 256, 0, stream>>>(outp, 512, W_ih_f1, W_ih_r1,
        b_ih_f1, b_hh_f1, b_ih_r1, b_hh_r1, xg);
    {
        const __half* xg_c = xg;
        unsigned int base1 = 4096u;
        void* args[] = {(void*)&xg_c, (void*)&W_hh_f1, (void*)&W_hh_r1,
                        (void*)&outp, (void*)&hbt, (void*)&base1};
        hipLaunchCooperativeKernel(reinterpret_cast<const void*>(recur2_kernel),
                                   dim3(256), dim3(256), args, RECUR_LDS, stream);
    }
}

// Round 5
// 5578.330 us; speedup vs baseline: 3.7631x; 1.0333x over previous
//
#include <hip/hip_runtime.h>
#include <hip/hip_fp16.h>

// Bidirectional 2-layer LSTM: B=32, T=1024, IN=256, H=256.
// ws layout: xg  f16 [2][32][1024][1024]          = 134,217,728 B
//            hbt u64 [2][16][2 parity][2 b][256]  =     262,144 B  (tagged h exchange)
// total = 134,479,872 B
//
// Tag protocol (per layer, base B): producer at step st stores (B+st+1, h) into
// parity st&1; consumer at step st polls parity (st+1)&1 for tag B+st.
// L0 base=1, L1 base=4096; hbt memset to 0 each launch (replay-safe).
//
// recur4: W_hh in VGPRs, HALF ROW per thread (128 f32 = 32 float4), thread
// covers BOTH batches over its k-half (W is batch-independent). ~175 VGPRs,
// __launch_bounds__(256,2) -> occupancy 2 blocks/CU so cooperative-launch
// validation passes with margin (round-4's ~300-VGPR/(256,1) variant silently
// failed to launch: all-zero output == stub absmax).
// Fallback if still zero: regular launch + >=81KB LDS forces 1 block/CU ->
// 256 blocks spread over 256 CUs, co-residency guaranteed without coop API.

#define T_LEN 1024
#define BATCH 32
#define HID   256
#define G4    1024
#define NS    8
#define NG    16

struct __align__(8) Half4 { __half x, y, z, w; };

__device__ __forceinline__ float sigm(float x) { return 1.0f / (1.0f + __expf(-x)); }
__device__ __forceinline__ float tanh_fast(float x) {
    float e = __expf(2.f * x);            // inf-safe
    return 1.f - 2.f / (e + 1.f);
}

// ---- projection: xg[dir][m][n] = sum_k A[m][k]*W[n][k] + bih[n] + bhh[n], stored f16 ----
__global__ __launch_bounds__(256) void proj_kernel(
    const float* __restrict__ A, int K,
    const float* __restrict__ Wf, const float* __restrict__ Wr,
    const float* __restrict__ bih_f, const float* __restrict__ bhh_f,
    const float* __restrict__ bih_r, const float* __restrict__ bhh_r,
    __half* __restrict__ xg)
{
    const int dir = blockIdx.z;
    const float* __restrict__ W   = dir ? Wr    : Wf;
    const float* __restrict__ bih = dir ? bih_r : bih_f;
    const float* __restrict__ bhh = dir ? bhh_r : bhh_f;
    __half* __restrict__ outp = xg + (size_t)dir * ((size_t)BATCH * T_LEN * G4);

    __shared__ float As[32][132];
    __shared__ float Bs[32][132];

    const int tid = threadIdx.x;
    const int tx  = tid & 15;
    const int ty  = tid >> 4;
    const int tx4 = tx * 4;
    const int ty4 = ty * 4;
    const int m0  = blockIdx.y * 128;
    const int n0  = blockIdx.x * 128;

    float acc[8][8];
    #pragma unroll
    for (int i = 0; i < 8; ++i)
        #pragma unroll
        for (int j = 0; j < 8; ++j) acc[i][j] = 0.f;

    for (int k0 = 0; k0 < K; k0 += 32) {
        #pragma unroll
        for (int it = 0; it < 4; ++it) {
            int f   = tid + it * 256;
            int row = f >> 3;
            int c4  = (f & 7) * 4;
            float4 av = *reinterpret_cast<const float4*>(&A[(size_t)(m0 + row) * K + k0 + c4]);
            float4 bv = *reinterpret_cast<const float4*>(&W[(size_t)(n0 + row) * K + k0 + c4]);
            As[c4 + 0][row] = av.x; As[c4 + 1][row] = av.y;
            As[c4 + 2][row] = av.z; As[c4 + 3][row] = av.w;
            Bs[c4 + 0][row] = bv.x; Bs[c4 + 1][row] = bv.y;
            Bs[c4 + 2][row] = bv.z; Bs[c4 + 3][row] = bv.w;
        }
        __syncthreads();
        #pragma unroll
        for (int k = 0; k < 32; ++k) {
            float4 a0 = *reinterpret_cast<const float4*>(&As[k][ty4]);
            float4 a1 = *reinterpret_cast<const float4*>(&As[k][64 + ty4]);
            float4 b0 = *reinterpret_cast<const float4*>(&Bs[k][tx4]);
            float4 b1 = *reinterpret_cast<const float4*>(&Bs[k][64 + tx4]);
            float a[8] = {a0.x,a0.y,a0.z,a0.w,a1.x,a1.y,a1.z,a1.w};
            float b[8] = {b0.x,b0.y,b0.z,b0.w,b1.x,b1.y,b1.z,b1.w};
            #pragma unroll
            for (int i = 0; i < 8; ++i)
                #pragma unroll
                for (int j = 0; j < 8; ++j)
                    acc[i][j] = fmaf(a[i], b[j], acc[i][j]);
        }
        __syncthreads();
    }

    float bb[8];
    #pragma unroll
    for (int j = 0; j < 8; ++j) {
        int n = n0 + ((j < 4) ? (tx4 + j) : (64 + tx4 + (j - 4)));
        bb[j] = bih[n] + bhh[n];
    }
    #pragma unroll
    for (int i = 0; i < 8; ++i) {
        int m = m0 + ((i < 4) ? (ty4 + i) : (64 + ty4 + (i - 4)));
        Half4 v0, v1;
        v0.x = __float2half(acc[i][0] + bb[0]);
        v0.y = __float2half(acc[i][1] + bb[1]);
        v0.z = __float2half(acc[i][2] + bb[2]);
        v0.w = __float2half(acc[i][3] + bb[3]);
        v1.x = __float2half(acc[i][4] + bb[4]);
        v1.y = __float2half(acc[i][5] + bb[5]);
        v1.z = __float2half(acc[i][6] + bb[6]);
        v1.w = __float2half(acc[i][7] + bb[7]);
        *reinterpret_cast<Half4*>(&outp[(size_t)m * G4 + n0 + tx4])      = v0;
        *reinterpret_cast<Half4*>(&outp[(size_t)m * G4 + n0 + 64 + tx4]) = v1;
    }
}

// ---- cooperative recurrence: W half-row in VGPRs, both batches per thread ----
// wg = (dir d, batch-group g, slice s). bid = a*64 + m*8 + x; gid=a*8+x; d=gid>>4,
// g=gid&15, s=m (group members share bid%8 -> likely same XCD; perf only).
// thread: col = tid&127 (q=col>>5 gate, jl=col&31, n_my=q*256+s*32+jl),
//         kh = tid>>7 (k-half). Waves are kh-uniform -> h reads are broadcasts.
extern "C" __global__ __launch_bounds__(256, 2) void recur4_kernel(
    const __half* __restrict__ xg,
    const float* __restrict__ Whh_f,           // [1024][256]
    const float* __restrict__ Whh_r,
    float* __restrict__ outp,                  // [32][1024][512]
    unsigned long long* __restrict__ hbt,      // [2][16][2][2][256] tagged
    unsigned int tagbase)
{
    __shared__ float hl[2 * HID];    // staged h [b][256]
    __shared__ float scr[2 * 256];   // partial gates [kh][b][128 col]

    const int tid = threadIdx.x;
    const int bid = blockIdx.x;
    const int x = bid & 7, m = (bid >> 3) & 7, a = bid >> 6;
    const int gid = a * 8 + x;
    const int d = gid >> 4;
    const int g = gid & 15;
    const int s = m;
    const float* __restrict__ Whh = d ? Whh_r : Whh_f;

    const int col  = tid & 127;
    const int kh   = tid >> 7;                    // k-half 0/1
    const int q    = col >> 5;
    const int jl   = col & 31;
    const int n_my = (q << 8) + s * 32 + jl;      // global gate row in W_hh
    const int kof  = kh * 128;

    // --- one-time: this thread's half W_hh row (128 f32) into 32 float4 VGPRs ---
    float4 wv[32];
    {
        const float* wrow = Whh + (size_t)n_my * HID + kof;
        #pragma unroll
        for (int k4 = 0; k4 < 32; ++k4)
            wv[k4] = *reinterpret_cast<const float4*>(&wrow[k4 * 4]);
    }

    unsigned long long* hb = hbt + (size_t)(d * NG + g) * 1024;  // [parity][2][256]

    // init: h[-1]=0, tag=tagbase, parity 1, own 64 slots
    const int bi0 = tid >> 5, jl0 = tid & 31;     // epilogue roles (tid<64)
    if (tid < 64) {
        __hip_atomic_store(&hb[512 + bi0 * HID + s * 32 + jl0],
                           (unsigned long long)tagbase << 32,
                           __ATOMIC_RELAXED, __HIP_MEMORY_SCOPE_AGENT);
    }

    // xg source: this thread adds xg(b = g*2 + kh, n_my) to batch-kh's partial
    const int b_x = g * 2 + kh;
    const __half* __restrict__ xgp =
        xg + ((size_t)(d * BATCH + b_x)) * T_LEN * G4 + n_my;

    const int i0 = tid * 2;              // this thread's 2 exchange slots
    float c_state = 0.f;                 // tid<64: cell of (bi0, s*32+jl0)

    for (int st = 0; st < T_LEN; ++st) {
        const int t = d ? (T_LEN - 1 - st) : st;

        // prefetch xg (independent of h) before polling
        float xv = __half2float(xgp[(size_t)t * G4]);

        // poll own 2 tagged slots of parity (st+1)&1 for tag tagbase+st
        {
            const unsigned int exp = tagbase + (unsigned)st;
            unsigned long long* hsrc = hb + (size_t)((st + 1) & 1) * 512;
            unsigned long long v0 = __hip_atomic_load(&hsrc[i0],     __ATOMIC_RELAXED, __HIP_MEMORY_SCOPE_AGENT);
            unsigned long long v1 = __hip_atomic_load(&hsrc[i0 + 1], __ATOMIC_RELAXED, __HIP_MEMORY_SCOPE_AGENT);
            while ((unsigned int)(v0 >> 32) != exp)
                v0 = __hip_atomic_load(&hsrc[i0],     __ATOMIC_RELAXED, __HIP_MEMORY_SCOPE_AGENT);
            while ((unsigned int)(v1 >> 32) != exp)
                v1 = __hip_atomic_load(&hsrc[i0 + 1], __ATOMIC_RELAXED, __HIP_MEMORY_SCOPE_AGENT);
            hl[i0]     = __uint_as_float((unsigned int)v0);
            hl[i0 + 1] = __uint_as_float((unsigned int)v1);
        }
        __syncthreads();   // hl ready (also orders prev-step scr reads vs this-step writes)

        // partial dots over this k-half, both batches, W in registers
        float p0a = (kh == 0) ? xv : 0.f, p0b = 0.f, p0c = 0.f, p0d = 0.f;
        float p1a = (kh == 1) ? xv : 0.f, p1b = 0.f, p1c = 0.f, p1d = 0.f;
        {
            const float* h0P = hl + kof;          // batch 0, this k-half
            const float* h1P = hl + HID + kof;    // batch 1
            #pragma unroll
            for (int k4 = 0; k4 < 32; ++k4) {
                float4 ha = *reinterpret_cast<const float4*>(&h0P[k4 * 4]);
                float4 hbv = *reinterpret_cast<const float4*>(&h1P[k4 * 4]);
                p0a = fmaf(ha.x, wv[k4].x, p0a);
                p0b = fmaf(ha.y, wv[k4].y, p0b);
                p0c = fmaf(ha.z, wv[k4].z, p0c);
                p0d = fmaf(ha.w, wv[k4].w, p0d);
                p1a = fmaf(hbv.x, wv[k4].x, p1a);
                p1b = fmaf(hbv.y, wv[k4].y, p1b);
                p1c = fmaf(hbv.z, wv[k4].z, p1c);
                p1d = fmaf(hbv.w, wv[k4].w, p1d);
            }
        }
        scr[kh * 256 +       col] = (p0a + p0b) + (p0c + p0d);   // batch 0 partial
        scr[kh * 256 + 128 + col] = (p1a + p1b) + (p1c + p1d);   // batch 1 partial
        __syncthreads();

        if (tid < 64) {
            float gi = scr[bi0 * 128 +       jl0] + scr[256 + bi0 * 128 +       jl0];
            float gf = scr[bi0 * 128 +  32 + jl0] + scr[256 + bi0 * 128 +  32 + jl0];
            float gg = scr[bi0 * 128 +  64 + jl0] + scr[256 + bi0 * 128 +  64 + jl0];
            float go = scr[bi0 * 128 +  96 + jl0] + scr[256 + bi0 * 128 +  96 + jl0];
            float ii = sigm(gi);
            float ff = sigm(gf);
            float g2 = tanh_fast(gg);
            float oo = sigm(go);
            c_state = ff * c_state + ii * g2;
            float h = oo * tanh_fast(c_state);
            int j = s * 32 + jl0;
            unsigned long long pv =
                ((unsigned long long)(tagbase + (unsigned)st + 1u) << 32) | __float_as_uint(h);
            __hip_atomic_store(&hb[(size_t)(st & 1) * 512 + bi0 * HID + j], pv,
                               __ATOMIC_RELAXED, __HIP_MEMORY_SCOPE_AGENT);
            int b = g * 2 + bi0;
            outp[((size_t)b * T_LEN + t) * (2 * HID) + d * HID + j] = h;
        }
        // next step's post-hl-write barrier orders scr reuse; hl slots are
        // per-thread-exclusive so early hl writes of step st+1 are safe.
    }
}

extern "C" void kernel_launch(void* const* d_in, const int* in_sizes, int n_in,
                              void* d_out, int out_size, void* d_ws, size_t ws_size,
                              hipStream_t stream)
{
    const float* x       = (const float*)d_in[0];
    const float* W_ih_f0 = (const float*)d_in[1];
    const float* W_hh_f0 = (const float*)d_in[2];
    const float* b_ih_f0 = (const float*)d_in[3];
    const float* b_hh_f0 = (const float*)d_in[4];
    const float* W_ih_r0 = (const float*)d_in[5];
    const float* W_hh_r0 = (const float*)d_in[6];
    const float* b_ih_r0 = (const float*)d_in[7];
    const float* b_hh_r0 = (const float*)d_in[8];
    const float* W_ih_f1 = (const float*)d_in[9];
    const float* W_hh_f1 = (const float*)d_in[10];
    const float* b_ih_f1 = (const float*)d_in[11];
    const float* b_hh_f1 = (const float*)d_in[12];
    const float* W_ih_r1 = (const float*)d_in[13];
    const float* W_hh_r1 = (const float*)d_in[14];
    const float* b_ih_r1 = (const float*)d_in[15];
    const float* b_hh_r1 = (const float*)d_in[16];

    float* outp = (float*)d_out;

    __half* xg = (__half*)d_ws;
    const size_t xg_bytes = (size_t)2 * BATCH * T_LEN * G4 * sizeof(__half); // 134,217,728
    unsigned long long* hbt = (unsigned long long*)((char*)d_ws + xg_bytes); // 262,144 B

    // clean tag space every launch (no stale-tag pre-match, fully replay-safe)
    hipMemsetAsync(hbt, 0, 262144, stream);

    // ---- layer 0 ----
    proj_kernel<<<dim3(8, 256, 2), 256, 0, stream>>>(x, 256, W_ih_f0, W_ih_r0,
        b_ih_f0, b_hh_f0, b_ih_r0, b_hh_r0, xg);
    {
        const __half* xg_c = xg;
        unsigned int base0 = 1u;
        void* args[] = {(void*)&xg_c, (void*)&W_hh_f0, (void*)&W_hh_r0,
                        (void*)&outp, (void*)&hbt, (void*)&base0};
        hipLaunchCooperativeKernel(reinterpret_cast<const void*>(recur4_kernel),
                                   dim3(256), dim3(256), args, 0, stream);
    }

    // ---- layer 1 ----
    proj_kernel<<<dim3(8, 256, 2), 256, 0, stream>>>(outp, 512, W_ih_f1, W_ih_r1,
        b_ih_f1, b_hh_f1, b_ih_r1, b_hh_r1, xg);
    {
        const __half* xg_c = xg;
        unsigned int base1 = 4096u;
        void* args[] = {(void*)&xg_c, (void*)&W_hh_f1, (void*)&W_hh_r1,
                        (void*)&outp, (void*)&hbt, (void*)&base1};
        hipLaunchCooperativeKernel(reinterpret_cast<const void*>(recur4_kernel),
                                   dim3(256), dim3(256), args, 0, stream);
    }
}